// Round 1
// baseline (75.979 us; speedup 1.0000x reference)
//
#include <hip/hip_runtime.h>

// Problem constants (from reference setup_inputs):
//   B=32, L=4096, V=10, F=1024, D=64
// out[1, b*D+d, l] = sum_f fp_table[idx[b,l], f] * W[d, f] + bias[d]
//
// FUSED single-kernel design (no workspace!):
//   - One 1024-thread block per output row r = b*64 + d  (2048 blocks).
//   - Each row needs only P[d][v] for v=0..9 (10 dot products of length
//     1024). Waves 0..9 each compute one dot: 8 KB of L2-resident reads,
//     4 float4 FMA iterations, 6-step shuffle reduce. ~10K MACs/block.
//   - idx int4 load is issued BEFORE phase 1 so HBM latency hides under
//     the dot products.
//   - Phase 2: LDS broadcast lookup (10 words -> 10 banks, duplicates
//     broadcast, conflict-free) + coalesced float4 store of the row.
// Eliminating d_ws removes the Pt round-trip, the second launch, the
// inter-kernel dependency, and any interaction with the harness's
// 256 MiB workspace re-poison fill (the 43 us dispatches in rocprof).
#define B_SIZE 32
#define L_SIZE 4096
#define V_SIZE 10
#define F_SIZE 1024
#define D_SIZE 64
#define L4     (L_SIZE / 4)   // 1024 float4 per output row

__global__ __launch_bounds__(1024) void fused_fp_embed(
    const int* __restrict__ idx,
    const float* __restrict__ fp_table,
    const float* __restrict__ W,
    const float* __restrict__ bias,
    float* __restrict__ out) {
  const int r    = blockIdx.x;     // output row, 0..2047
  const int b    = r >> 6;         // batch
  const int d    = r & 63;         // dim
  const int t    = threadIdx.x;    // 0..1023
  const int wv   = t >> 6;         // wave id, 0..15
  const int lane = t & 63;

  __shared__ float Pd[16];         // 10 used, padded

  // Issue the idx load early: 16B/lane, wave-contiguous 1KB segments.
  // Latency hides under phase 1 below.
  const int4 vi = ((const int4*)idx)[b * L4 + t];

  // ---- Phase 1: waves 0..9 each compute P[d][wv] ----
  if (wv < V_SIZE) {
    const float4* ft4 = (const float4*)(fp_table + wv * F_SIZE);
    const float4* w4  = (const float4*)(W + d * F_SIZE);
    float sum = 0.f;
    // F/4 = 256 float4, 64 lanes -> 4 iterations
    #pragma unroll
    for (int i = 0; i < 4; ++i) {
      float4 a = ft4[lane + 64 * i];
      float4 w = w4[lane + 64 * i];
      sum += a.x * w.x + a.y * w.y + a.z * w.z + a.w * w.w;
    }
    // full-wave butterfly reduction
    #pragma unroll
    for (int off = 32; off > 0; off >>= 1)
      sum += __shfl_down(sum, off, 64);
    if (lane == 0) Pd[wv] = sum + bias[d];
  }
  __syncthreads();

  // ---- Phase 2: gather + coalesced store ----
  // 64 lanes read among 10 consecutive LDS words: distinct banks,
  // duplicates broadcast -> conflict-free.
  float4 o;
  o.x = Pd[vi.x];
  o.y = Pd[vi.y];
  o.z = Pd[vi.z];
  o.w = Pd[vi.w];
  ((float4*)out)[r * L4 + t] = o;
}

extern "C" void kernel_launch(void* const* d_in, const int* in_sizes, int n_in,
                              void* d_out, int out_size, void* d_ws, size_t ws_size,
                              hipStream_t stream) {
  const int*   idx      = (const int*)d_in[0];    // [B, L] int32
  const float* fp_table = (const float*)d_in[1];  // [V, F]
  const float* W        = (const float*)d_in[2];  // [D, F]
  const float* bias     = (const float*)d_in[3];  // [D]
  float* out = (float*)d_out;                     // [1, B*D, L] fp32
  (void)d_ws; (void)ws_size;                      // workspace intentionally unused

  fused_fp_embed<<<B_SIZE * D_SIZE, 1024, 0, stream>>>(idx, fp_table, W, bias, out);
}